// Round 1
// baseline (229.632 us; speedup 1.0000x reference)
//
#include <hip/hip_runtime.h>

typedef _Float16 half8_t __attribute__((ext_vector_type(8)));
typedef _Float16 half4_t __attribute__((ext_vector_type(4)));
typedef _Float16 half2_t __attribute__((ext_vector_type(2)));
typedef float f32x4 __attribute__((ext_vector_type(4)));

#define S_LEN 2048
#define D_DIM 64
#define SD (S_LEN * D_DIM)
#define BC 64
#define NKT (S_LEN / BC)   // 32 key tiles
#define LDK 72             // f16 row stride (64 + 8 pad, keeps 16B align, spreads banks)
#define LDO 68             // f32 row stride for epilogue

// One workgroup = 64 q-rows of one (b,h); wave w owns q rows [16w,16w+16).
// S^T = K*Q^T formulation: softmax stats land per q = lane&15 (2 shfls only).
__global__ __launch_bounds__(256, 3)
void fattn_kernel(const float* __restrict__ Qg, const float* __restrict__ Kg,
                  const float* __restrict__ Vg, const int* __restrict__ Mg,
                  float* __restrict__ Og) {
  __shared__ __align__(16) char smem[27648];
  _Float16* Ksh  = (_Float16*)smem;             // [64 keys][72] f16 row-major
  _Float16* VTsh = (_Float16*)(smem + 9216);    // [64 d][72] f16 (key-fastest = V^T)
  _Float16* Psh  = (_Float16*)(smem + 18432);   // 4 waves x [16 q][72] f16
  float*    Osh  = (float*)smem;                // [64][68] f32, epilogue reuse

  const int t = threadIdx.x;
  const int w = t >> 6;
  const int lane = t & 63;
  const int g = lane >> 4;   // quad
  const int c = lane & 15;

  const int qt = blockIdx.x & 31;
  const int bh = blockIdx.x >> 5;   // same-head blocks adjacent -> L2 locality
  const int b = bh >> 3;            // H = 8
  const int qb = qt * 64;

  const float* Qb = Qg + (size_t)bh * SD;
  const float* Kb = Kg + (size_t)bh * SD;
  const float* Vb = Vg + (size_t)bh * SD;
  const int*   Mb = Mg + (size_t)b * S_LEN;
  float*       Ob = Og + (size_t)bh * SD;

  // ---- Q^T B-frags for this wave's q = qb + 16w + c; fold 1/8 * log2(e) ----
  const float qscale = 0.125f * 1.44269504088896340736f;
  half8_t qf[2];
  {
    const float* qp = Qb + (size_t)(qb + 16 * w + c) * D_DIM + 8 * g;
#pragma unroll
    for (int ks = 0; ks < 2; ++ks) {
      float4 lo = *(const float4*)(qp + 32 * ks);
      float4 hi = *(const float4*)(qp + 32 * ks + 4);
      half8_t h;
      h[0] = (_Float16)(lo.x * qscale); h[1] = (_Float16)(lo.y * qscale);
      h[2] = (_Float16)(lo.z * qscale); h[3] = (_Float16)(lo.w * qscale);
      h[4] = (_Float16)(hi.x * qscale); h[5] = (_Float16)(hi.y * qscale);
      h[6] = (_Float16)(hi.z * qscale); h[7] = (_Float16)(hi.w * qscale);
      qf[ks] = h;
    }
  }

  f32x4 acc[4];
#pragma unroll
  for (int i = 0; i < 4; ++i)
#pragma unroll
    for (int j = 0; j < 4; ++j) acc[i][j] = 0.f;
  float mrun = -1e30f;  // per q=c running max (log2 domain)
  float lrun = 0.f;     // per q=c running denom

  _Float16* Pw = Psh + w * 16 * LDK;

  for (int kt = 0; kt < NKT; ++kt) {
    const int kb = kt * BC;
    __syncthreads();  // previous iter's frag reads done before overwrite

    // ---- stage K tile -> f16 row-major LDS (coalesced float4, b64 writes) ----
#pragma unroll
    for (int it = 0; it < 4; ++it) {
      int f = it * 256 + t;
      int row = f >> 4;
      int c4 = f & 15;
      float4 v = *(const float4*)(Kb + (size_t)(kb + row) * D_DIM + c4 * 4);
      half4_t h;
      h[0] = (_Float16)v.x; h[1] = (_Float16)v.y;
      h[2] = (_Float16)v.z; h[3] = (_Float16)v.w;
      *(half4_t*)(Ksh + row * LDK + c4 * 4) = h;
    }
    // ---- stage V tile transposed -> VT[d][key] f16 (2x2 blocks, b32 writes) ----
    {
      const int kpl = t & 7;
      const int p = t >> 3;      // d-pair 0..31
      const int d0 = 2 * p;
#pragma unroll
      for (int kc = 0; kc < 4; ++kc) {
        int kp = kpl + 8 * kc;   // key-pair 0..31
        const float* vp = Vb + (size_t)(kb + 2 * kp) * D_DIM + d0;
        float2 va  = *(const float2*)(vp);
        float2 vb2 = *(const float2*)(vp + D_DIM);
        half2_t h0; h0.x = (_Float16)va.x; h0.y = (_Float16)vb2.x;
        half2_t h1; h1.x = (_Float16)va.y; h1.y = (_Float16)vb2.y;
        *(half2_t*)(VTsh + d0 * LDK + 2 * kp) = h0;
        *(half2_t*)(VTsh + (d0 + 1) * LDK + 2 * kp) = h1;
      }
    }
    __syncthreads();

    // ---- S^T = K . Q^T : sT[mt] holds key = 16mt+4g+r, q = c ----
    f32x4 sT[4];
#pragma unroll
    for (int mt = 0; mt < 4; ++mt) {
      f32x4 z;
      z[0] = 0.f; z[1] = 0.f; z[2] = 0.f; z[3] = 0.f;
#pragma unroll
      for (int ks = 0; ks < 2; ++ks) {
        half8_t kf = *(half8_t*)(Ksh + (16 * mt + c) * LDK + ks * 32 + 8 * g);
        z = __builtin_amdgcn_mfma_f32_16x16x32_f16(kf, qf[ks], z, 0, 0, 0);
      }
      sT[mt] = z;
    }

    // ---- key-padding mask: masked -> exactly -1e30 ----
#pragma unroll
    for (int mt = 0; mt < 4; ++mt) {
      int4 mv = *(const int4*)(Mb + kb + 16 * mt + 4 * g);
      sT[mt][0] = mv.x ? sT[mt][0] : -1e30f;
      sT[mt][1] = mv.y ? sT[mt][1] : -1e30f;
      sT[mt][2] = mv.z ? sT[mt][2] : -1e30f;
      sT[mt][3] = mv.w ? sT[mt][3] : -1e30f;
    }

    // ---- online softmax stats (per q = c; reduce over 16 regs + 2 shfls) ----
    float tmax = sT[0][0];
#pragma unroll
    for (int mt = 0; mt < 4; ++mt)
#pragma unroll
      for (int r = 0; r < 4; ++r) tmax = fmaxf(tmax, sT[mt][r]);
    tmax = fmaxf(tmax, __shfl_xor(tmax, 16));
    tmax = fmaxf(tmax, __shfl_xor(tmax, 32));
    float mnew = fmaxf(mrun, tmax);
    float alpha = __builtin_amdgcn_exp2f(mrun - mnew);  // first iter: exp2(-inf)=0
    mrun = mnew;

    float lt = 0.f;
#pragma unroll
    for (int mt = 0; mt < 4; ++mt) {
#pragma unroll
      for (int r = 0; r < 4; ++r) {
        float pv = __builtin_amdgcn_exp2f(sT[mt][r] - mnew);
        lt += pv;
        Pw[c * LDK + 16 * mt + 4 * g + r] = (_Float16)pv;  // P[q][key] row-major
      }
    }
    lt += __shfl_xor(lt, 16);
    lt += __shfl_xor(lt, 32);
    lrun = lrun * alpha + lt;

#pragma unroll
    for (int mt = 0; mt < 4; ++mt) {
      acc[mt][0] *= alpha; acc[mt][1] *= alpha;
      acc[mt][2] *= alpha; acc[mt][3] *= alpha;
    }

    // ---- O^T += V^T . P^T  (A=V^T frag, B=P^T frag, both contiguous b128) ----
#pragma unroll
    for (int ks = 0; ks < 2; ++ks) {
      half8_t pf = *(half8_t*)(Pw + c * LDK + ks * 32 + 8 * g);
#pragma unroll
      for (int mt = 0; mt < 4; ++mt) {
        half8_t vf = *(half8_t*)(VTsh + (16 * mt + c) * LDK + ks * 32 + 8 * g);
        acc[mt] = __builtin_amdgcn_mfma_f32_16x16x32_f16(vf, pf, acc[mt], 0, 0, 0);
      }
    }
  }

  // ---- epilogue: /l, transpose O^T -> O via LDS, coalesced float4 stores ----
  __syncthreads();
  {
    float linv = 1.f / lrun;
#pragma unroll
    for (int mt = 0; mt < 4; ++mt)
#pragma unroll
      for (int r = 0; r < 4; ++r)
        Osh[(16 * w + c) * LDO + 16 * mt + 4 * g + r] = acc[mt][r] * linv;
  }
  __syncthreads();
  {
    int q = t >> 2;
    int f4 = t & 3;
#pragma unroll
    for (int i = 0; i < 4; ++i) {
      f32x4 o = *(f32x4*)(Osh + q * LDO + (f4 + 4 * i) * 4);
      *(float4*)(Ob + (size_t)(qb + q) * D_DIM + (f4 + 4 * i) * 4) =
          make_float4(o.x, o.y, o.z, o.w);
    }
  }
}

extern "C" void kernel_launch(void* const* d_in, const int* in_sizes, int n_in,
                              void* d_out, int out_size, void* d_ws, size_t ws_size,
                              hipStream_t stream) {
  (void)in_sizes; (void)n_in; (void)d_ws; (void)ws_size; (void)out_size;
  const float* Q = (const float*)d_in[0];
  const float* K = (const float*)d_in[1];
  const float* V = (const float*)d_in[2];
  const int*   M = (const int*)d_in[3];
  float* O = (float*)d_out;
  // grid: 32 q-tiles (fast) x 32 (b,h) -> same-head blocks adjacent
  fattn_kernel<<<dim3(32 * 32), dim3(256), 0, stream>>>(Q, K, V, M, O);
}

// Round 2
// 169.643 us; speedup vs baseline: 1.3536x; 1.3536x over previous
//
#include <hip/hip_runtime.h>

typedef _Float16 half8_t __attribute__((ext_vector_type(8)));
typedef _Float16 half4_t __attribute__((ext_vector_type(4)));
typedef _Float16 half2_t __attribute__((ext_vector_type(2)));
typedef float f32x4 __attribute__((ext_vector_type(4)));

#define S_LEN 2048
#define D_DIM 64
#define SD (S_LEN * D_DIM)
#define BC 64
#define NKT (S_LEN / BC)   // 32 key tiles
#define LDK 72             // f16 row stride (64 + 8 pad)
#define LDO 68             // f32 row stride for epilogue

// 512 threads = 8 waves; wave w owns q rows [16w,16w+16) of a 128-q block tile.
// S^T = K*Q^T formulation: softmax stats land per q = lane&15 (2 shfls only).
// Next K/V tile is prefetched into registers during compute (hides global lat).
__global__ __launch_bounds__(512, 4)
void fattn_kernel(const float* __restrict__ Qg, const float* __restrict__ Kg,
                  const float* __restrict__ Vg, const int* __restrict__ Mg,
                  float* __restrict__ Og) {
  __shared__ __align__(16) char smem[45056];
  _Float16* Ksh  = (_Float16*)smem;             // [64 keys][72] f16
  _Float16* VTsh = (_Float16*)(smem + 9216);    // [64 d][72] f16 (V^T)
  _Float16* Psh  = (_Float16*)(smem + 18432);   // 8 waves x [16 q][72] f16
  int*      Msh  = (int*)(smem + 36864);        // [2048] key mask
  float*    Osh  = (float*)smem;                // [128][68] f32, epilogue reuse

  const int t = threadIdx.x;
  const int w = t >> 6;
  const int lane = t & 63;
  const int g = lane >> 4;   // quad
  const int c = lane & 15;

  const int qt = blockIdx.x & 15;
  const int bh = blockIdx.x >> 4;   // same-head blocks adjacent -> L2 locality
  const int qb = qt * 128;

  const float* Qb = Qg + (size_t)bh * SD;
  const float* Kb = Kg + (size_t)bh * SD;
  const float* Vb = Vg + (size_t)bh * SD;
  const int*   Mb = Mg + (size_t)(bh >> 3) * S_LEN;  // H = 8
  float*       Ob = Og + (size_t)bh * SD;

  // ---- stage full key mask -> LDS once (coalesced b128 both ways) ----
  *(int4*)(Msh + 4 * t) = *(const int4*)(Mb + 4 * t);

  // ---- Q^T B-frags for q = qb + 16w + c; fold 1/8 * log2(e) ----
  const float qscale = 0.125f * 1.44269504088896340736f;
  half8_t qf[2];
  {
    const float* qp = Qb + (size_t)(qb + 16 * w + c) * D_DIM + 8 * g;
#pragma unroll
    for (int ks = 0; ks < 2; ++ks) {
      float4 lo = *(const float4*)(qp + 32 * ks);
      float4 hi = *(const float4*)(qp + 32 * ks + 4);
      half8_t h;
      h[0] = (_Float16)(lo.x * qscale); h[1] = (_Float16)(lo.y * qscale);
      h[2] = (_Float16)(lo.z * qscale); h[3] = (_Float16)(lo.w * qscale);
      h[4] = (_Float16)(hi.x * qscale); h[5] = (_Float16)(hi.y * qscale);
      h[6] = (_Float16)(hi.z * qscale); h[7] = (_Float16)(hi.w * qscale);
      qf[ks] = h;
    }
  }

  // ---- staging coordinates (512 threads) ----
  const int krow0 = t >> 4;   // K row = krow0 + 32*it
  const int kc4   = t & 15;   // K float4 column
  const int vp    = t >> 4;   // V d-pair 0..31
  const int vkpl  = t & 15;   // V key-pair low; kp = vkpl + 16*kc

  // ---- preload tile 0 into registers ----
  float4 kr[2];
  float2 vr[4];
#pragma unroll
  for (int it = 0; it < 2; ++it)
    kr[it] = *(const float4*)(Kb + (size_t)(krow0 + 32 * it) * D_DIM + kc4 * 4);
#pragma unroll
  for (int kc = 0; kc < 2; ++kc) {
    const float* vpp = Vb + (size_t)(2 * (vkpl + 16 * kc)) * D_DIM + 2 * vp;
    vr[2 * kc]     = *(const float2*)(vpp);
    vr[2 * kc + 1] = *(const float2*)(vpp + D_DIM);
  }

  f32x4 acc[4];
#pragma unroll
  for (int i = 0; i < 4; ++i)
#pragma unroll
    for (int j = 0; j < 4; ++j) acc[i][j] = 0.f;
  float mrun = -1e30f;
  float lrun = 0.f;

  _Float16* Pw = Psh + w * 16 * LDK;

  for (int kt = 0; kt < NKT; ++kt) {
    const int kb = kt * BC;
    __syncthreads();  // prev iter's frag reads done before overwrite

    // ---- cvt prefetched regs -> LDS ----
#pragma unroll
    for (int it = 0; it < 2; ++it) {
      half4_t h;
      h[0] = (_Float16)kr[it].x; h[1] = (_Float16)kr[it].y;
      h[2] = (_Float16)kr[it].z; h[3] = (_Float16)kr[it].w;
      *(half4_t*)(Ksh + (krow0 + 32 * it) * LDK + kc4 * 4) = h;
    }
#pragma unroll
    for (int kc = 0; kc < 2; ++kc) {
      int kp = vkpl + 16 * kc;
      half2_t h0; h0.x = (_Float16)vr[2 * kc].x;     h0.y = (_Float16)vr[2 * kc + 1].x;
      half2_t h1; h1.x = (_Float16)vr[2 * kc].y;     h1.y = (_Float16)vr[2 * kc + 1].y;
      *(half2_t*)(VTsh + (2 * vp) * LDK + 2 * kp) = h0;
      *(half2_t*)(VTsh + (2 * vp + 1) * LDK + 2 * kp) = h1;
    }

    // ---- issue next tile's global loads (fly across compute) ----
    if (kt < NKT - 1) {
      const int kb2 = kb + BC;
#pragma unroll
      for (int it = 0; it < 2; ++it)
        kr[it] = *(const float4*)(Kb + (size_t)(kb2 + krow0 + 32 * it) * D_DIM + kc4 * 4);
#pragma unroll
      for (int kc = 0; kc < 2; ++kc) {
        const float* vpp = Vb + (size_t)(kb2 + 2 * (vkpl + 16 * kc)) * D_DIM + 2 * vp;
        vr[2 * kc]     = *(const float2*)(vpp);
        vr[2 * kc + 1] = *(const float2*)(vpp + D_DIM);
      }
    }
    __syncthreads();

    // ---- mask (broadcast LDS reads, no global in chain) ----
    int4 mv[4];
#pragma unroll
    for (int mt = 0; mt < 4; ++mt)
      mv[mt] = *(const int4*)(Msh + kb + 16 * mt + 4 * g);

    // ---- S^T = K . Q^T : sT[mt] holds key = 16mt+4g+r, q = c ----
    f32x4 sT[4];
#pragma unroll
    for (int mt = 0; mt < 4; ++mt) {
      f32x4 z;
      z[0] = 0.f; z[1] = 0.f; z[2] = 0.f; z[3] = 0.f;
#pragma unroll
      for (int ks = 0; ks < 2; ++ks) {
        half8_t kf = *(half8_t*)(Ksh + (16 * mt + c) * LDK + ks * 32 + 8 * g);
        z = __builtin_amdgcn_mfma_f32_16x16x32_f16(kf, qf[ks], z, 0, 0, 0);
      }
      sT[mt] = z;
    }

    // ---- key-padding mask: masked -> exactly -1e30 ----
#pragma unroll
    for (int mt = 0; mt < 4; ++mt) {
      sT[mt][0] = mv[mt].x ? sT[mt][0] : -1e30f;
      sT[mt][1] = mv[mt].y ? sT[mt][1] : -1e30f;
      sT[mt][2] = mv[mt].z ? sT[mt][2] : -1e30f;
      sT[mt][3] = mv[mt].w ? sT[mt][3] : -1e30f;
    }

    // ---- online softmax (per q = c): tree-max over 16 regs + 2 shfls ----
    float tm[4];
#pragma unroll
    for (int mt = 0; mt < 4; ++mt)
      tm[mt] = fmaxf(fmaxf(sT[mt][0], sT[mt][1]), fmaxf(sT[mt][2], sT[mt][3]));
    float tmax = fmaxf(fmaxf(tm[0], tm[1]), fmaxf(tm[2], tm[3]));
    tmax = fmaxf(tmax, __shfl_xor(tmax, 16));
    tmax = fmaxf(tmax, __shfl_xor(tmax, 32));
    float mnew = fmaxf(mrun, tmax);
    float alpha = __builtin_amdgcn_exp2f(mrun - mnew);
    mrun = mnew;

    float lt = 0.f;
#pragma unroll
    for (int mt = 0; mt < 4; ++mt) {
      float pv0 = __builtin_amdgcn_exp2f(sT[mt][0] - mnew);
      float pv1 = __builtin_amdgcn_exp2f(sT[mt][1] - mnew);
      float pv2 = __builtin_amdgcn_exp2f(sT[mt][2] - mnew);
      float pv3 = __builtin_amdgcn_exp2f(sT[mt][3] - mnew);
      lt += (pv0 + pv1) + (pv2 + pv3);
      half4_t ph;
      ph[0] = (_Float16)pv0; ph[1] = (_Float16)pv1;
      ph[2] = (_Float16)pv2; ph[3] = (_Float16)pv3;
      *(half4_t*)(Pw + c * LDK + 16 * mt + 4 * g) = ph;  // b64 write
    }
    lt += __shfl_xor(lt, 16);
    lt += __shfl_xor(lt, 32);
    lrun = lrun * alpha + lt;

#pragma unroll
    for (int mt = 0; mt < 4; ++mt) {
      acc[mt][0] *= alpha; acc[mt][1] *= alpha;
      acc[mt][2] *= alpha; acc[mt][3] *= alpha;
    }

    // ---- O^T += V^T . P^T  (A=V^T frag, B=P^T frag, contiguous b128) ----
#pragma unroll
    for (int ks = 0; ks < 2; ++ks) {
      half8_t pf = *(half8_t*)(Pw + c * LDK + ks * 32 + 8 * g);
#pragma unroll
      for (int mt = 0; mt < 4; ++mt) {
        half8_t vf = *(half8_t*)(VTsh + (16 * mt + c) * LDK + ks * 32 + 8 * g);
        acc[mt] = __builtin_amdgcn_mfma_f32_16x16x32_f16(vf, pf, acc[mt], 0, 0, 0);
      }
    }
  }

  // ---- epilogue: /l, transpose O^T -> O via LDS, coalesced stores ----
  __syncthreads();
  {
    float linv = 1.f / lrun;
#pragma unroll
    for (int mt = 0; mt < 4; ++mt)
#pragma unroll
      for (int r = 0; r < 4; ++r)
        Osh[(16 * w + c) * LDO + 16 * mt + 4 * g + r] = acc[mt][r] * linv;
  }
  __syncthreads();
  {
    int q = t >> 2;         // 0..127
    int f4 = t & 3;
#pragma unroll
    for (int i = 0; i < 4; ++i) {
      f32x4 o = *(f32x4*)(Osh + q * LDO + (f4 + 4 * i) * 4);
      *(float4*)(Ob + (size_t)(qb + q) * D_DIM + (f4 + 4 * i) * 4) =
          make_float4(o.x, o.y, o.z, o.w);
    }
  }
}

extern "C" void kernel_launch(void* const* d_in, const int* in_sizes, int n_in,
                              void* d_out, int out_size, void* d_ws, size_t ws_size,
                              hipStream_t stream) {
  (void)in_sizes; (void)n_in; (void)d_ws; (void)ws_size; (void)out_size;
  const float* Q = (const float*)d_in[0];
  const float* K = (const float*)d_in[1];
  const float* V = (const float*)d_in[2];
  const int*   M = (const int*)d_in[3];
  float* O = (float*)d_out;
  // grid: 16 q-tiles (fast) x 32 (b,h)
  fattn_kernel<<<dim3(16 * 32), dim3(512), 0, stream>>>(Q, K, V, M, O);
}

// Round 4
// 157.389 us; speedup vs baseline: 1.4590x; 1.0779x over previous
//
#include <hip/hip_runtime.h>

typedef _Float16 half8_t __attribute__((ext_vector_type(8)));
typedef _Float16 half4_t __attribute__((ext_vector_type(4)));
typedef _Float16 half2_t __attribute__((ext_vector_type(2)));
typedef __fp16 fp16x2 __attribute__((ext_vector_type(2)));
typedef float f32x4 __attribute__((ext_vector_type(4)));

#define S_LEN 2048
#define D_DIM 64
#define SD (S_LEN * D_DIM)
#define BC 64
#define NKT (S_LEN / BC)   // 32 key tiles
#define LDK 72             // f16 row stride (64 + 8 pad)
#define LDO 68             // f32 row stride for epilogue

// 512 threads = 8 waves; wave w owns q rows [16w,16w+16) of a 128-q tile.
// S^T = K*Q^T: softmax stats land per q = lane&15 (2 shfls only).
// Double-buffered K/V LDS tiles -> ONE barrier/iter; next tile's globals
// prefetched into registers one full iteration ahead.
__global__ __launch_bounds__(512, 4)
void fattn_kernel(const float* __restrict__ Qg, const float* __restrict__ Kg,
                  const float* __restrict__ Vg, const int* __restrict__ Mg,
                  float* __restrict__ Og) {
  __shared__ __align__(16) char smem[63488];
  // K buf0 [0,9216) K buf1 [9216,18432) V buf0 [18432,27648) V buf1 [27648,36864)
  _Float16* Psh = (_Float16*)(smem + 36864);  // 8 waves x [16 q][72] f16
  int*      Msh = (int*)(smem + 55296);       // [2048] key mask
  float*    Osh = (float*)smem;               // [128][68] f32, epilogue reuse

  const int t = threadIdx.x;
  const int w = t >> 6;
  const int lane = t & 63;
  const int g = lane >> 4;   // quad
  const int c = lane & 15;

  // bh in low bits: all 16 q-blocks of one (b,h) hit the SAME XCD (i%8==bh%8)
  const int bh = blockIdx.x & 31;
  const int qt = blockIdx.x >> 5;
  const int qb = qt * 128;

  const float* Qb = Qg + (size_t)bh * SD;
  const float* Kb = Kg + (size_t)bh * SD;
  const float* Vb = Vg + (size_t)bh * SD;
  const int*   Mb = Mg + (size_t)(bh >> 3) * S_LEN;  // H = 8
  float*       Ob = Og + (size_t)bh * SD;

  // ---- stage full key mask -> LDS once ----
  *(int4*)(Msh + 4 * t) = *(const int4*)(Mb + 4 * t);

  // ---- Q^T B-frags for q = qb + 16w + c; fold 1/8 * log2(e) ----
  const float qscale = 0.125f * 1.44269504088896340736f;
  half8_t qf[2];
  {
    const float* qp = Qb + (size_t)(qb + 16 * w + c) * D_DIM + 8 * g;
#pragma unroll
    for (int ks = 0; ks < 2; ++ks) {
      float4 lo = *(const float4*)(qp + 32 * ks);
      float4 hi = *(const float4*)(qp + 32 * ks + 4);
      fp16x2 p0 = __builtin_amdgcn_cvt_pkrtz(lo.x * qscale, lo.y * qscale);
      fp16x2 p1 = __builtin_amdgcn_cvt_pkrtz(lo.z * qscale, lo.w * qscale);
      fp16x2 p2 = __builtin_amdgcn_cvt_pkrtz(hi.x * qscale, hi.y * qscale);
      fp16x2 p3 = __builtin_amdgcn_cvt_pkrtz(hi.z * qscale, hi.w * qscale);
      half8_t h;
      h[0] = (_Float16)p0[0]; h[1] = (_Float16)p0[1];
      h[2] = (_Float16)p1[0]; h[3] = (_Float16)p1[1];
      h[4] = (_Float16)p2[0]; h[5] = (_Float16)p2[1];
      h[6] = (_Float16)p3[0]; h[7] = (_Float16)p3[1];
      qf[ks] = h;
    }
  }

  // ---- staging coordinates (512 threads) ----
  const int krow0 = t >> 4;   // K row = krow0 + 32*it
  const int kc4   = t & 15;   // K float4 column
  const int vp    = t >> 4;   // V d-pair 0..31
  const int vkpl  = t & 15;   // V key-pair low; kp = vkpl + 16*kc

  float4 kr[2];
  float2 vr[4];
  auto prefetch = [&](int kb2) {
#pragma unroll
    for (int it = 0; it < 2; ++it)
      kr[it] = *(const float4*)(Kb + (size_t)(kb2 + krow0 + 32 * it) * D_DIM + kc4 * 4);
#pragma unroll
    for (int kc = 0; kc < 2; ++kc) {
      const float* vpp = Vb + (size_t)(kb2 + 2 * (vkpl + 16 * kc)) * D_DIM + 2 * vp;
      vr[2 * kc]     = *(const float2*)(vpp);
      vr[2 * kc + 1] = *(const float2*)(vpp + D_DIM);
    }
  };
  auto stage = [&](int buf) {
    _Float16* Kd = (_Float16*)(smem + 9216 * buf);
    _Float16* Vd = (_Float16*)(smem + 18432 + 9216 * buf);
#pragma unroll
    for (int it = 0; it < 2; ++it) {
      fp16x2 a  = __builtin_amdgcn_cvt_pkrtz(kr[it].x, kr[it].y);
      fp16x2 b2 = __builtin_amdgcn_cvt_pkrtz(kr[it].z, kr[it].w);
      half4_t h;
      h[0] = (_Float16)a[0]; h[1] = (_Float16)a[1];
      h[2] = (_Float16)b2[0]; h[3] = (_Float16)b2[1];
      *(half4_t*)(Kd + (krow0 + 32 * it) * LDK + kc4 * 4) = h;
    }
#pragma unroll
    for (int kc = 0; kc < 2; ++kc) {
      int kp = vkpl + 16 * kc;
      fp16x2 h0 = __builtin_amdgcn_cvt_pkrtz(vr[2 * kc].x, vr[2 * kc + 1].x);
      fp16x2 h1 = __builtin_amdgcn_cvt_pkrtz(vr[2 * kc].y, vr[2 * kc + 1].y);
      half2_t g0; g0[0] = (_Float16)h0[0]; g0[1] = (_Float16)h0[1];
      half2_t g1; g1[0] = (_Float16)h1[0]; g1[1] = (_Float16)h1[1];
      *(half2_t*)(Vd + (2 * vp) * LDK + 2 * kp) = g0;
      *(half2_t*)(Vd + (2 * vp + 1) * LDK + 2 * kp) = g1;
    }
  };

  f32x4 acc[4];
#pragma unroll
  for (int i = 0; i < 4; ++i)
#pragma unroll
    for (int j = 0; j < 4; ++j) acc[i][j] = 0.f;
  float mrun = -1e30f;
  float lrun = 0.f;

  _Float16* Pw = Psh + w * 16 * LDK;

  // prologue: tile0 -> buf0; tile1 in flight
  prefetch(0);
  stage(0);
  prefetch(BC);
  __syncthreads();

  for (int kt = 0; kt < NKT; ++kt) {
    const int kb = kt * BC;
    const int cur = kt & 1;

    // ---- stage tile kt+1 (regs prefetched last iter) into the other buffer;
    //      issue prefetch of tile kt+2 ----
    if (kt < NKT - 1) stage(cur ^ 1);
    if (kt < NKT - 2) prefetch(kb + 2 * BC);

    const _Float16* Kc = (const _Float16*)(smem + 9216 * cur);
    const _Float16* Vc = (const _Float16*)(smem + 18432 + 9216 * cur);

    // ---- mask (broadcast LDS reads) ----
    int4 mv[4];
#pragma unroll
    for (int mt = 0; mt < 4; ++mt)
      mv[mt] = *(const int4*)(Msh + kb + 16 * mt + 4 * g);

    // ---- S^T = K . Q^T : sT[mt] holds key = 16mt+4g+r, q = c ----
    f32x4 sT[4];
#pragma unroll
    for (int mt = 0; mt < 4; ++mt) {
      f32x4 z;
      z[0] = 0.f; z[1] = 0.f; z[2] = 0.f; z[3] = 0.f;
#pragma unroll
      for (int ks = 0; ks < 2; ++ks) {
        half8_t kf = *(half8_t*)(Kc + (16 * mt + c) * LDK + ks * 32 + 8 * g);
        z = __builtin_amdgcn_mfma_f32_16x16x32_f16(kf, qf[ks], z, 0, 0, 0);
      }
      sT[mt] = z;
    }

    // ---- key-padding mask: masked -> exactly -1e30 ----
#pragma unroll
    for (int mt = 0; mt < 4; ++mt) {
      sT[mt][0] = mv[mt].x ? sT[mt][0] : -1e30f;
      sT[mt][1] = mv[mt].y ? sT[mt][1] : -1e30f;
      sT[mt][2] = mv[mt].z ? sT[mt][2] : -1e30f;
      sT[mt][3] = mv[mt].w ? sT[mt][3] : -1e30f;
    }

    // ---- online softmax (per q = c): tree-max + 2 shfls ----
    float tm[4];
#pragma unroll
    for (int mt = 0; mt < 4; ++mt)
      tm[mt] = fmaxf(fmaxf(sT[mt][0], sT[mt][1]), fmaxf(sT[mt][2], sT[mt][3]));
    float tmax = fmaxf(fmaxf(tm[0], tm[1]), fmaxf(tm[2], tm[3]));
    tmax = fmaxf(tmax, __shfl_xor(tmax, 16));
    tmax = fmaxf(tmax, __shfl_xor(tmax, 32));
    float mnew = fmaxf(mrun, tmax);
    float alpha = __builtin_amdgcn_exp2f(mrun - mnew);
    mrun = mnew;

    float lt = 0.f;
#pragma unroll
    for (int mt = 0; mt < 4; ++mt) {
      float pv0 = __builtin_amdgcn_exp2f(sT[mt][0] - mnew);
      float pv1 = __builtin_amdgcn_exp2f(sT[mt][1] - mnew);
      float pv2 = __builtin_amdgcn_exp2f(sT[mt][2] - mnew);
      float pv3 = __builtin_amdgcn_exp2f(sT[mt][3] - mnew);
      lt += (pv0 + pv1) + (pv2 + pv3);
      fp16x2 p01 = __builtin_amdgcn_cvt_pkrtz(pv0, pv1);
      fp16x2 p23 = __builtin_amdgcn_cvt_pkrtz(pv2, pv3);
      half4_t ph;
      ph[0] = (_Float16)p01[0]; ph[1] = (_Float16)p01[1];
      ph[2] = (_Float16)p23[0]; ph[3] = (_Float16)p23[1];
      *(half4_t*)(Pw + c * LDK + 16 * mt + 4 * g) = ph;  // b64 write
    }
    lt += __shfl_xor(lt, 16);
    lt += __shfl_xor(lt, 32);
    lrun = lrun * alpha + lt;

#pragma unroll
    for (int mt = 0; mt < 4; ++mt) {
      acc[mt][0] *= alpha; acc[mt][1] *= alpha;
      acc[mt][2] *= alpha; acc[mt][3] *= alpha;
    }

    // ---- O^T += V^T . P^T  (A=V^T frag, B=P^T frag, contiguous b128) ----
#pragma unroll
    for (int ks = 0; ks < 2; ++ks) {
      half8_t pf = *(half8_t*)(Pw + c * LDK + ks * 32 + 8 * g);
#pragma unroll
      for (int mt = 0; mt < 4; ++mt) {
        half8_t vf = *(half8_t*)(Vc + (16 * mt + c) * LDK + ks * 32 + 8 * g);
        acc[mt] = __builtin_amdgcn_mfma_f32_16x16x32_f16(vf, pf, acc[mt], 0, 0, 0);
      }
    }

    __syncthreads();  // single barrier: guards next iter's buffer swap
  }

  // ---- epilogue: /l, transpose O^T -> O via LDS, coalesced stores ----
  {
    float linv = 1.f / lrun;
#pragma unroll
    for (int mt = 0; mt < 4; ++mt)
#pragma unroll
      for (int r = 0; r < 4; ++r)
        Osh[(16 * w + c) * LDO + 16 * mt + 4 * g + r] = acc[mt][r] * linv;
  }
  __syncthreads();
  {
    int q = t >> 2;         // 0..127
    int f4 = t & 3;
#pragma unroll
    for (int i = 0; i < 4; ++i) {
      f32x4 o = *(f32x4*)(Osh + q * LDO + (f4 + 4 * i) * 4);
      *(float4*)(Ob + (size_t)(qb + q) * D_DIM + (f4 + 4 * i) * 4) =
          make_float4(o.x, o.y, o.z, o.w);
    }
  }
}

extern "C" void kernel_launch(void* const* d_in, const int* in_sizes, int n_in,
                              void* d_out, int out_size, void* d_ws, size_t ws_size,
                              hipStream_t stream) {
  (void)in_sizes; (void)n_in; (void)d_ws; (void)ws_size; (void)out_size;
  const float* Q = (const float*)d_in[0];
  const float* K = (const float*)d_in[1];
  const float* V = (const float*)d_in[2];
  const int*   M = (const int*)d_in[3];
  float* O = (float*)d_out;
  // grid: bh fast (XCD locality), 16 q-tiles slow
  fattn_kernel<<<dim3(32 * 16), dim3(512), 0, stream>>>(Q, K, V, M, O);
}

// Round 5
// 155.810 us; speedup vs baseline: 1.4738x; 1.0101x over previous
//
#include <hip/hip_runtime.h>

typedef _Float16 half8_t __attribute__((ext_vector_type(8)));
typedef _Float16 half4_t __attribute__((ext_vector_type(4)));
typedef _Float16 half2_t __attribute__((ext_vector_type(2)));
typedef __fp16 fp16x2 __attribute__((ext_vector_type(2)));
typedef float f32x4 __attribute__((ext_vector_type(4)));

#define S_LEN 2048
#define D_DIM 64
#define SD (S_LEN * D_DIM)
#define BC 64
#define NKT (S_LEN / BC)   // 32 key tiles
#define LDK 72             // f16 row stride (64 + 8 pad)
#define LDO 68             // f32 row stride for epilogue

// 256 threads = 4 waves; wave w owns q rows [32w,32w+32) as two 16-q groups.
// K/V LDS fragments are read ONCE per wave-iter and reused for both groups
// (halves the dominant LDS-read traffic vs 16q/wave). Double-buffered K/V,
// one barrier/iter, register prefetch one tile ahead, additive f32 mask.
__global__ __launch_bounds__(256, 2)
void fattn_kernel(const float* __restrict__ Qg, const float* __restrict__ Kg,
                  const float* __restrict__ Vg, const int* __restrict__ Mg,
                  float* __restrict__ Og) {
  __shared__ __align__(16) char smem[63488];
  // K buf0 [0,9216) K buf1 [9216,18432) V buf0 [18432,27648) V buf1 [27648,36864)
  _Float16* Psh = (_Float16*)(smem + 36864);  // 4 waves x [32 q][72] f16
  float*    Msh = (float*)(smem + 55296);     // [2048] additive mask {0,-1e30}
  float*    Osh = (float*)smem;               // [128][68] f32, epilogue reuse

  const int t = threadIdx.x;
  const int w = t >> 6;
  const int lane = t & 63;
  const int g = lane >> 4;   // quad
  const int c = lane & 15;

  // bh in low bits: all 16 q-blocks of one (b,h) hit the SAME XCD
  const int bh = blockIdx.x & 31;
  const int qt = blockIdx.x >> 5;
  const int qb = qt * 128;

  const float* Qb = Qg + (size_t)bh * SD;
  const float* Kb = Kg + (size_t)bh * SD;
  const float* Vb = Vg + (size_t)bh * SD;
  const int*   Mb = Mg + (size_t)(bh >> 3) * S_LEN;  // H = 8
  float*       Ob = Og + (size_t)bh * SD;

  // ---- stage additive mask -> LDS once: (m-1)*1e30 -> {0, -1e30} ----
  {
    int4 m0 = *(const int4*)(Mb + 8 * t);
    int4 m1 = *(const int4*)(Mb + 8 * t + 4);
    float4 f0, f1;
    f0.x = (float)(m0.x - 1) * 1e30f; f0.y = (float)(m0.y - 1) * 1e30f;
    f0.z = (float)(m0.z - 1) * 1e30f; f0.w = (float)(m0.w - 1) * 1e30f;
    f1.x = (float)(m1.x - 1) * 1e30f; f1.y = (float)(m1.y - 1) * 1e30f;
    f1.z = (float)(m1.z - 1) * 1e30f; f1.w = (float)(m1.w - 1) * 1e30f;
    *(float4*)(Msh + 8 * t) = f0;
    *(float4*)(Msh + 8 * t + 4) = f1;
  }

  // ---- Q^T B-frags for q = qb + 32w + 16h + c; fold 1/8 * log2(e) ----
  const float qscale = 0.125f * 1.44269504088896340736f;
  half8_t qf[2][2];
#pragma unroll
  for (int h = 0; h < 2; ++h) {
    const float* qp = Qb + (size_t)(qb + 32 * w + 16 * h + c) * D_DIM + 8 * g;
#pragma unroll
    for (int ks = 0; ks < 2; ++ks) {
      float4 lo = *(const float4*)(qp + 32 * ks);
      float4 hi = *(const float4*)(qp + 32 * ks + 4);
      fp16x2 p0 = __builtin_amdgcn_cvt_pkrtz(lo.x * qscale, lo.y * qscale);
      fp16x2 p1 = __builtin_amdgcn_cvt_pkrtz(lo.z * qscale, lo.w * qscale);
      fp16x2 p2 = __builtin_amdgcn_cvt_pkrtz(hi.x * qscale, hi.y * qscale);
      fp16x2 p3 = __builtin_amdgcn_cvt_pkrtz(hi.z * qscale, hi.w * qscale);
      half8_t hh;
      hh[0] = (_Float16)p0[0]; hh[1] = (_Float16)p0[1];
      hh[2] = (_Float16)p1[0]; hh[3] = (_Float16)p1[1];
      hh[4] = (_Float16)p2[0]; hh[5] = (_Float16)p2[1];
      hh[6] = (_Float16)p3[0]; hh[7] = (_Float16)p3[1];
      qf[h][ks] = hh;
    }
  }

  // ---- staging coordinates (256 threads) ----
  const int krow0 = t >> 4;   // 0..15; K row = krow0 + 16*it
  const int kc4   = t & 15;   // K float4 column
  const int vp    = t >> 3;   // V d-pair 0..31
  const int vkpl  = t & 7;    // V key-pair low; kp = vkpl + 8*kc

  float4 kr[4];
  float2 vr[8];
  auto prefetch = [&](int kb2) {
#pragma unroll
    for (int it = 0; it < 4; ++it)
      kr[it] = *(const float4*)(Kb + (size_t)(kb2 + krow0 + 16 * it) * D_DIM + kc4 * 4);
#pragma unroll
    for (int kc = 0; kc < 4; ++kc) {
      const float* vpp = Vb + (size_t)(kb2 + 2 * (vkpl + 8 * kc)) * D_DIM + 2 * vp;
      vr[2 * kc]     = *(const float2*)(vpp);
      vr[2 * kc + 1] = *(const float2*)(vpp + D_DIM);
    }
  };
  auto stage = [&](int buf) {
    _Float16* Kd = (_Float16*)(smem + 9216 * buf);
    _Float16* Vd = (_Float16*)(smem + 18432 + 9216 * buf);
#pragma unroll
    for (int it = 0; it < 4; ++it) {
      fp16x2 a  = __builtin_amdgcn_cvt_pkrtz(kr[it].x, kr[it].y);
      fp16x2 b2 = __builtin_amdgcn_cvt_pkrtz(kr[it].z, kr[it].w);
      half4_t h;
      h[0] = (_Float16)a[0]; h[1] = (_Float16)a[1];
      h[2] = (_Float16)b2[0]; h[3] = (_Float16)b2[1];
      *(half4_t*)(Kd + (krow0 + 16 * it) * LDK + kc4 * 4) = h;
    }
#pragma unroll
    for (int kc = 0; kc < 4; ++kc) {
      int kp = vkpl + 8 * kc;
      fp16x2 h0 = __builtin_amdgcn_cvt_pkrtz(vr[2 * kc].x, vr[2 * kc + 1].x);
      fp16x2 h1 = __builtin_amdgcn_cvt_pkrtz(vr[2 * kc].y, vr[2 * kc + 1].y);
      half2_t g0; g0[0] = (_Float16)h0[0]; g0[1] = (_Float16)h0[1];
      half2_t g1; g1[0] = (_Float16)h1[0]; g1[1] = (_Float16)h1[1];
      *(half2_t*)(Vd + (2 * vp) * LDK + 2 * kp) = g0;
      *(half2_t*)(Vd + (2 * vp + 1) * LDK + 2 * kp) = g1;
    }
  };

  f32x4 acc[2][4];
#pragma unroll
  for (int h = 0; h < 2; ++h)
#pragma unroll
    for (int i = 0; i < 4; ++i)
#pragma unroll
      for (int j = 0; j < 4; ++j) acc[h][i][j] = 0.f;
  float mrun[2] = {-1e30f, -1e30f};
  float lrun[2] = {0.f, 0.f};

  _Float16* Pw = Psh + w * 32 * LDK;

  // prologue: tile0 -> buf0; tile1 in flight
  prefetch(0);
  stage(0);
  prefetch(BC);
  __syncthreads();

  for (int kt = 0; kt < NKT; ++kt) {
    const int kb = kt * BC;
    const int cur = kt & 1;

    if (kt < NKT - 1) stage(cur ^ 1);
    if (kt < NKT - 2) prefetch(kb + 2 * BC);

    const _Float16* Kc = (const _Float16*)(smem + 9216 * cur);
    const _Float16* Vc = (const _Float16*)(smem + 18432 + 9216 * cur);

    // ---- additive mask (broadcast LDS reads) ----
    f32x4 mvf[4];
#pragma unroll
    for (int mt = 0; mt < 4; ++mt)
      mvf[mt] = *(const f32x4*)(Msh + kb + 16 * mt + 4 * g);

    // ---- S^T = K . Q^T for both q-groups; K frag read ONCE ----
    f32x4 sT[2][4];
#pragma unroll
    for (int mt = 0; mt < 4; ++mt) {
      f32x4 z0, z1;
#pragma unroll
      for (int j = 0; j < 4; ++j) { z0[j] = 0.f; z1[j] = 0.f; }
#pragma unroll
      for (int ks = 0; ks < 2; ++ks) {
        half8_t kf = *(half8_t*)(Kc + (16 * mt + c) * LDK + ks * 32 + 8 * g);
        z0 = __builtin_amdgcn_mfma_f32_16x16x32_f16(kf, qf[0][ks], z0, 0, 0, 0);
        z1 = __builtin_amdgcn_mfma_f32_16x16x32_f16(kf, qf[1][ks], z1, 0, 0, 0);
      }
      sT[0][mt] = z0;
      sT[1][mt] = z1;
    }

    // ---- mask add (exactly reference semantics: s + (1-m)*(-1e30)) ----
#pragma unroll
    for (int h = 0; h < 2; ++h)
#pragma unroll
      for (int mt = 0; mt < 4; ++mt)
#pragma unroll
        for (int r = 0; r < 4; ++r) sT[h][mt][r] += mvf[mt][r];

    // ---- online softmax per group (per q = c): tree-max + 2 shfls ----
#pragma unroll
    for (int h = 0; h < 2; ++h) {
      float tm[4];
#pragma unroll
      for (int mt = 0; mt < 4; ++mt)
        tm[mt] = fmaxf(fmaxf(sT[h][mt][0], sT[h][mt][1]),
                       fmaxf(sT[h][mt][2], sT[h][mt][3]));
      float tmax = fmaxf(fmaxf(tm[0], tm[1]), fmaxf(tm[2], tm[3]));
      tmax = fmaxf(tmax, __shfl_xor(tmax, 16));
      tmax = fmaxf(tmax, __shfl_xor(tmax, 32));
      float mnew = fmaxf(mrun[h], tmax);
      float alpha = __builtin_amdgcn_exp2f(mrun[h] - mnew);
      mrun[h] = mnew;

      float lt = 0.f;
      _Float16* Pr = Pw + (16 * h + c) * LDK;
#pragma unroll
      for (int mt = 0; mt < 4; ++mt) {
        float pv0 = __builtin_amdgcn_exp2f(sT[h][mt][0] - mnew);
        float pv1 = __builtin_amdgcn_exp2f(sT[h][mt][1] - mnew);
        float pv2 = __builtin_amdgcn_exp2f(sT[h][mt][2] - mnew);
        float pv3 = __builtin_amdgcn_exp2f(sT[h][mt][3] - mnew);
        lt += (pv0 + pv1) + (pv2 + pv3);
        fp16x2 p01 = __builtin_amdgcn_cvt_pkrtz(pv0, pv1);
        fp16x2 p23 = __builtin_amdgcn_cvt_pkrtz(pv2, pv3);
        half4_t ph;
        ph[0] = (_Float16)p01[0]; ph[1] = (_Float16)p01[1];
        ph[2] = (_Float16)p23[0]; ph[3] = (_Float16)p23[1];
        *(half4_t*)(Pr + 16 * mt + 4 * g) = ph;  // b64 write
      }
      lt += __shfl_xor(lt, 16);
      lt += __shfl_xor(lt, 32);
      lrun[h] = lrun[h] * alpha + lt;

#pragma unroll
      for (int mt = 0; mt < 4; ++mt) {
        acc[h][mt][0] *= alpha; acc[h][mt][1] *= alpha;
        acc[h][mt][2] *= alpha; acc[h][mt][3] *= alpha;
      }
    }

    // ---- O^T += V^T . P^T ; V frags read ONCE into regs, reused per group ----
    half8_t vf[4][2];
#pragma unroll
    for (int mt = 0; mt < 4; ++mt)
#pragma unroll
      for (int ks = 0; ks < 2; ++ks)
        vf[mt][ks] = *(half8_t*)(Vc + (16 * mt + c) * LDK + ks * 32 + 8 * g);
#pragma unroll
    for (int h = 0; h < 2; ++h) {
#pragma unroll
      for (int ks = 0; ks < 2; ++ks) {
        half8_t pf = *(half8_t*)(Pw + (16 * h + c) * LDK + ks * 32 + 8 * g);
#pragma unroll
        for (int mt = 0; mt < 4; ++mt)
          acc[h][mt] = __builtin_amdgcn_mfma_f32_16x16x32_f16(vf[mt][ks], pf,
                                                              acc[h][mt], 0, 0, 0);
      }
    }

    __syncthreads();  // single barrier: guards next iter's buffer swap
  }

  // ---- epilogue: /l, transpose O^T -> O via LDS, coalesced stores ----
#pragma unroll
  for (int h = 0; h < 2; ++h) {
    float linv = 1.f / lrun[h];
#pragma unroll
    for (int mt = 0; mt < 4; ++mt)
#pragma unroll
      for (int r = 0; r < 4; ++r)
        Osh[(32 * w + 16 * h + c) * LDO + 16 * mt + 4 * g + r] = acc[h][mt][r] * linv;
  }
  __syncthreads();
  {
    int f8 = t & 7;
#pragma unroll
    for (int i = 0; i < 4; ++i) {
      int q = (t >> 3) + 32 * i;
#pragma unroll
      for (int j = 0; j < 2; ++j) {
        int c4 = f8 + 8 * j;
        f32x4 o = *(f32x4*)(Osh + q * LDO + c4 * 4);
        *(float4*)(Ob + (size_t)(qb + q) * D_DIM + c4 * 4) =
            make_float4(o.x, o.y, o.z, o.w);
      }
    }
  }
}

extern "C" void kernel_launch(void* const* d_in, const int* in_sizes, int n_in,
                              void* d_out, int out_size, void* d_ws, size_t ws_size,
                              hipStream_t stream) {
  (void)in_sizes; (void)n_in; (void)d_ws; (void)ws_size; (void)out_size;
  const float* Q = (const float*)d_in[0];
  const float* K = (const float*)d_in[1];
  const float* V = (const float*)d_in[2];
  const int*   M = (const int*)d_in[3];
  float* O = (float*)d_out;
  // grid: bh fast (XCD locality), 16 q-tiles slow
  fattn_kernel<<<dim3(32 * 16), dim3(256), 0, stream>>>(Q, K, V, M, O);
}